// Round 13
// baseline (440.503 us; speedup 1.0000x reference)
//
#include <hip/hip_runtime.h>

#define NN 50000
#define NE 800000
#define NG 1000
#define DIN 64
#define HIDC 64
#define GOUTC 256
#define FPC 2048
#define H1C 1024
#define H2C 512
#define MOUTC 256
#define D1C 512
#define EPSV 1e-5f
#define SLOPEV 0.2f
#define NB 196  // ceil(NN/256)

typedef __attribute__((ext_vector_type(8))) short s8v;
typedef __attribute__((ext_vector_type(4))) float f4v;
typedef unsigned short ushort_t;

__device__ inline ushort_t f2b(float f) {
    unsigned u = __builtin_bit_cast(unsigned, f);
    unsigned r = (u + 0x7FFFu + ((u >> 16) & 1u)) >> 16;
    return (ushort_t)r;
}
__device__ inline float b2f(ushort_t u) {
    return __builtin_bit_cast(float, ((unsigned)u) << 16);
}

// ---- GAT: xl_bf = bf16(x @ Wg^T) ; a_src/a_dst ; also zeroes deg ----
__global__ void k_xl(const float* __restrict__ x, const float* __restrict__ Wg,
                     const float* __restrict__ att_src, const float* __restrict__ att_dst,
                     ushort_t* __restrict__ xl_bf, float* __restrict__ a_src,
                     float* __restrict__ a_dst, int* __restrict__ deg) {
    __shared__ float Wgs[64][65];
    __shared__ float xs[4][64];
    int t = threadIdx.x;
    int lane = t & 63;
    int w = t >> 6;
    if (blockIdx.x < NB) {
        int i = blockIdx.x * 256 + t;
        if (i < NN) deg[i] = 0;
    }
    for (int i = t; i < 64 * 64; i += 256) Wgs[i >> 6][i & 63] = Wg[i];
    int node = blockIdx.x * 4 + w;
    xs[w][lane] = x[node * 64 + lane];
    __syncthreads();
    float acc = 0.f;
#pragma unroll
    for (int d = 0; d < 64; ++d) acc += xs[w][d] * Wgs[lane][d];
    xl_bf[node * 64 + lane] = f2b(acc);
    float vs = acc * att_src[lane];
    float vd = acc * att_dst[lane];
#pragma unroll
    for (int off = 32; off > 0; off >>= 1) {
        vs += __shfl_xor(vs, off);
        vd += __shfl_xor(vd, off);
    }
    if (lane == 0) { a_src[node] = vs; a_dst[node] = vd; }
}

// ---- CSR build: degree histogram ----
__global__ void k_deg(const int* __restrict__ ei, int* __restrict__ deg) {
    int e = blockIdx.x * 256 + threadIdx.x;
    if (e < NE) atomicAdd(&deg[ei[NE + e]], 1);
}

// ---- CSR build: per-block sums; also zeroes gsum/gcnt ----
__global__ __launch_bounds__(256) void k_scan1(const int* __restrict__ deg,
                                               int* __restrict__ blocksum,
                                               float* __restrict__ gsum,
                                               int* __restrict__ gcnt) {
    int b = blockIdx.x, t = threadIdx.x;
    int tid = b * 256 + t;
    if (tid < NG * 64) gsum[tid] = 0.f;
    int tid2 = tid + NB * 256;
    if (tid2 < NG * 64) gsum[tid2] = 0.f;
    if (tid < NG) gcnt[tid] = 0;
    int v = (tid < NN) ? deg[tid] : 0;
#pragma unroll
    for (int off = 32; off > 0; off >>= 1) v += __shfl_xor(v, off);
    __shared__ int ws[4];
    if ((t & 63) == 0) ws[t >> 6] = v;
    __syncthreads();
    if (t == 0) blocksum[b] = ws[0] + ws[1] + ws[2] + ws[3];
}

// ---- CSR build: block base + local 256-wide scan -> rowptr/cursor ----
__global__ __launch_bounds__(256) void k_scan2(const int* __restrict__ deg,
                                               const int* __restrict__ blocksum,
                                               int* __restrict__ rowptr,
                                               int* __restrict__ cursor) {
    int b = blockIdx.x, t = threadIdx.x;
    int v = (t < b) ? blocksum[t] : 0;  // NB=196 < 256
#pragma unroll
    for (int off = 32; off > 0; off >>= 1) v += __shfl_xor(v, off);
    __shared__ int ws[4];
    __shared__ int sc[256];
    if ((t & 63) == 0) ws[t >> 6] = v;
    int idx = b * 256 + t;
    int d = (idx < NN) ? deg[idx] : 0;
    sc[t] = d;
    __syncthreads();
    int base = ws[0] + ws[1] + ws[2] + ws[3];
    for (int off = 1; off < 256; off <<= 1) {
        int x = (t >= off) ? sc[t - off] : 0;
        __syncthreads();
        sc[t] += x;
        __syncthreads();
    }
    if (idx < NN) {
        int ex = base + sc[t] - d;
        rowptr[idx] = ex;
        cursor[idx] = ex;
    }
}

// ---- CSR build: scatter packed (src, weight) by dst ----
__global__ void k_scatter(const int* __restrict__ ei, const float* __restrict__ a_src,
                          const float* __restrict__ a_dst, int* __restrict__ cursor,
                          int2* __restrict__ csr_sw) {
    int e = blockIdx.x * 256 + threadIdx.x;
    if (e < NE) {
        int s = ei[e];
        int d = ei[NE + e];
        int pos = atomicAdd(&cursor[d], 1);
        float ev = a_src[s] + a_dst[d];
        ev = ev > 0.f ? ev : SLOPEV * ev;
        int2 v;
        v.x = s;
        v.y = __float_as_int(expf(ev));
        csr_sw[pos] = v;
    }
}

// ---- fused gather: weighted aggregation + bias + relu + mean-pool ----
__global__ void k_gather(const int2* __restrict__ csr_sw, const int* __restrict__ rowptr,
                         const int* __restrict__ deg, const ushort_t* __restrict__ xl_bf,
                         const float* __restrict__ a_src, const float* __restrict__ a_dst,
                         const float* __restrict__ gat_bias, const int* __restrict__ batch,
                         float* __restrict__ gsum, int* __restrict__ gcnt) {
    int t = threadIdx.x, lane = t & 63, w = t >> 6;
    int n = blockIdx.x * 4 + w;
    float ev = a_src[n] + a_dst[n];
    ev = ev > 0.f ? ev : SLOPEV * ev;
    float ex = expf(ev);
    float den = ex;
    float acc = ex * b2f(xl_bf[(size_t)n * 64 + lane]);
    int beg = rowptr[n];
    int end = beg + deg[n];
    for (int j = beg; j < end; j += 8) {
        int s[8];
        float wt[8];
#pragma unroll
        for (int u = 0; u < 8; ++u) {
            int jj = j + u;
            int2 v = csr_sw[jj];          // csr_sw padded +8: safe
            bool ok = jj < end;
            s[u] = ok ? v.x : n;
            wt[u] = ok ? __int_as_float(v.y) : 0.f;
        }
        float vv[8];
#pragma unroll
        for (int u = 0; u < 8; ++u) vv[u] = b2f(xl_bf[(size_t)s[u] * 64 + lane]);
#pragma unroll
        for (int u = 0; u < 8; ++u) {
            den += wt[u];
            acc += wt[u] * vv[u];
        }
    }
    float v = acc / den + gat_bias[lane];
    v = v > 0.f ? v : 0.f;
    int b = batch[n];
    atomicAdd(&gsum[b * 64 + lane], v);
    if (lane == 0) atomicAdd(&gcnt[b], 1);
}

// ---- fp32->bf16 conversion, 4 segments + optional pooled segment ----
__global__ void k_f2b4(const float* __restrict__ sa, ushort_t* __restrict__ da, int ca,
                       const float* __restrict__ sb, ushort_t* __restrict__ db, int cb,
                       const float* __restrict__ sc_, ushort_t* __restrict__ dc, int cc,
                       const float* __restrict__ sd, ushort_t* __restrict__ dd, int cd,
                       int na, int nb_, int nc, int nd,
                       const float* __restrict__ gsum, const int* __restrict__ gcnt,
                       ushort_t* __restrict__ pooled_bf) {
    int b = blockIdx.x;
    if (b >= cd) {  // pooled segment: NG*64 elems
        int i = ((b - cd) * 256 + threadIdx.x) * 8;
        if (i + 8 <= NG * 64) {
#pragma unroll
            for (int j = 0; j < 8; ++j) {
                float c = (float)gcnt[(i + j) >> 6];
                pooled_bf[i + j] = f2b(gsum[i + j] / fmaxf(c, 1.f));
            }
        } else {
            for (int j = i; j < NG * 64; ++j) {
                float c = (float)gcnt[j >> 6];
                pooled_bf[j] = f2b(gsum[j] / fmaxf(c, 1.f));
            }
        }
        return;
    }
    const float* s;
    ushort_t* d;
    int lb, n;
    if (b < ca) { s = sa; d = da; lb = b; n = na; }
    else if (b < cb) { s = sb; d = db; lb = b - ca; n = nb_; }
    else if (b < cc) { s = sc_; d = dc; lb = b - cb; n = nc; }
    else { s = sd; d = dd; lb = b - cc; n = nd; }
    int i = (lb * 256 + threadIdx.x) * 8;
    if (i + 8 <= n) {
#pragma unroll
        for (int j = 0; j < 8; ++j) d[i + j] = f2b(s[i + j]);
    } else {
        for (int j = i; j < n; ++j) d[j] = f2b(s[j]);
    }
}

// ---- bf16 MFMA GEMM, BK=64 ----
template <bool RELU, bool OBF16>
__global__ __launch_bounds__(256) void k_mgemm(const ushort_t* __restrict__ A,
                                               const ushort_t* __restrict__ B,
                                               const float* __restrict__ bias, void* Cv,
                                               int M, int N, int K, int ldc) {
    __shared__ ushort_t As[64][68];
    __shared__ ushort_t Bs[64][68];
    int t = threadIdx.x;
    int lane = t & 63, w = t >> 6;
    int wr = w >> 1, wc = w & 1;
    int bm = blockIdx.y * 64, bn = blockIdx.x * 64;
    f4v acc[2][2];
#pragma unroll
    for (int m = 0; m < 2; ++m)
#pragma unroll
        for (int n = 0; n < 2; ++n) acc[m][n] = (f4v){0.f, 0.f, 0.f, 0.f};

    int lr = t >> 2;
    int lk = (t & 3) * 16;
    int arow = bm + lr;
    bool aval = arow < M;
    const ushort_t* aptr = A + (size_t)(aval ? arow : (M - 1)) * K + lk;
    const ushort_t* bptr = B + (size_t)(bn + lr) * K + lk;
    int fr = lane & 15, kg = lane >> 4;

    for (int k0 = 0; k0 < K; k0 += 64) {
        s8v av0 = {}, av1 = {};
        if (aval) {
            av0 = *(const s8v*)(aptr + k0);
            av1 = *(const s8v*)(aptr + k0 + 8);
        }
        s8v bv0 = *(const s8v*)(bptr + k0);
        s8v bv1 = *(const s8v*)(bptr + k0 + 8);
        *(s8v*)&As[lr][lk] = av0;
        *(s8v*)&As[lr][lk + 8] = av1;
        *(s8v*)&Bs[lr][lk] = bv0;
        *(s8v*)&Bs[lr][lk + 8] = bv1;
        __syncthreads();
#pragma unroll
        for (int kk = 0; kk < 2; ++kk) {
            s8v b0 = *(const s8v*)&Bs[wc * 32 + fr][kk * 32 + kg * 8];
            s8v b1 = *(const s8v*)&Bs[wc * 32 + 16 + fr][kk * 32 + kg * 8];
#pragma unroll
            for (int m = 0; m < 2; ++m) {
                s8v af = *(const s8v*)&As[wr * 32 + m * 16 + fr][kk * 32 + kg * 8];
                acc[m][0] = __builtin_amdgcn_mfma_f32_16x16x32_bf16(af, b0, acc[m][0], 0, 0, 0);
                acc[m][1] = __builtin_amdgcn_mfma_f32_16x16x32_bf16(af, b1, acc[m][1], 0, 0, 0);
            }
        }
        __syncthreads();
    }
    int fq = lane >> 4;
#pragma unroll
    for (int m = 0; m < 2; ++m) {
        int row = bm + wr * 32 + m * 16 + fq * 4;
#pragma unroll
        for (int n = 0; n < 2; ++n) {
            int col = bn + wc * 32 + n * 16 + fr;
            float bb = bias[col];
#pragma unroll
            for (int r = 0; r < 4; ++r) {
                int gr = row + r;
                if (gr < M) {
                    float v = acc[m][n][r] + bb;
                    if (RELU) v = fmaxf(v, 0.f);
                    if (OBF16) ((ushort_t*)Cv)[(size_t)gr * ldc + col] = f2b(v);
                    else ((float*)Cv)[(size_t)gr * ldc + col] = v;
                }
            }
        }
    }
}

// ---- BN: slot partial sums (no atomics, no memset) ----
__global__ void k_bnpart(const float* __restrict__ h, float* __restrict__ psum,
                         float* __restrict__ psq, int ncols) {
    int col = blockIdx.x * 256 + threadIdx.x;
    int y = blockIdx.y;
    int r0 = y * 125;
    float s = 0.f, q = 0.f;
    for (int r = r0; r < r0 + 125; ++r) {
        float v = h[(size_t)r * ncols + col];
        s += v;
        q += v * v;
    }
    psum[y * 1024 + col] = s;
    psq[y * 1024 + col] = q;
}

// ---- BN normalize (slot reduce inline) + relu + bf16 ----
__global__ void k_bnrelu_bf(const float* __restrict__ h, const float* __restrict__ psum,
                            const float* __restrict__ psq, const float* __restrict__ gamma,
                            const float* __restrict__ beta, ushort_t* __restrict__ dst,
                            int colmask, int total) {
    int i = (blockIdx.x * 256 + threadIdx.x) * 4;
    if (i < total) {
#pragma unroll
        for (int j = 0; j < 4; ++j) {
            int col = (i + j) & colmask;
            float s = 0.f, q = 0.f;
#pragma unroll
            for (int y = 0; y < 8; ++y) {
                s += psum[y * 1024 + col];
                q += psq[y * 1024 + col];
            }
            float mu = s * (1.f / NG);
            float var = q * (1.f / NG) - mu * mu;
            float sc = gamma[col] * rsqrtf(var + EPSV);
            float sh = beta[col] - mu * sc;
            float v = h[i + j] * sc + sh;
            dst[i + j] = f2b(fmaxf(v, 0.f));
        }
    }
}

// ---- final: out[g] = sum_j bn(z[g,j]) * Wl[j] + bl (slot reduce inline) ----
__global__ void k_final(const float* __restrict__ z, const float* __restrict__ psum,
                        const float* __restrict__ psq, const float* __restrict__ gamma,
                        const float* __restrict__ beta, const float* __restrict__ Wl,
                        const float* __restrict__ bl, float* __restrict__ out) {
    int g = blockIdx.x;
    int t = threadIdx.x;
    float acc = 0.f;
    for (int j = t; j < D1C; j += 256) {
        float s = 0.f, q = 0.f;
#pragma unroll
        for (int y = 0; y < 8; ++y) {
            s += psum[y * 1024 + j];
            q += psq[y * 1024 + j];
        }
        float mu = s * (1.f / NG);
        float var = q * (1.f / NG) - mu * mu;
        float sc = gamma[j] * rsqrtf(var + EPSV);
        float sh = beta[j] - mu * sc;
        float v = z[g * D1C + j] * sc + sh;
        acc += v * Wl[j];
    }
#pragma unroll
    for (int off = 32; off > 0; off >>= 1) acc += __shfl_xor(acc, off);
    __shared__ float red[4];
    int lane = t & 63, w = t >> 6;
    if (lane == 0) red[w] = acc;
    __syncthreads();
    if (t == 0) out[g] = red[0] + red[1] + red[2] + red[3] + bl[0];
}

extern "C" void kernel_launch(void* const* d_in, const int* in_sizes, int n_in,
                              void* d_out, int out_size, void* d_ws, size_t ws_size,
                              hipStream_t stream) {
    const float* x       = (const float*)d_in[0];
    const int*   ei      = (const int*)d_in[1];
    const int*   batch   = (const int*)d_in[2];
    const float* fpts    = (const float*)d_in[3];
    const float* Wg      = (const float*)d_in[4];
    const float* att_src = (const float*)d_in[5];
    const float* att_dst = (const float*)d_in[6];
    const float* gat_b   = (const float*)d_in[7];
    const float* Wlg     = (const float*)d_in[8];
    const float* blg     = (const float*)d_in[9];
    const float* W1      = (const float*)d_in[10];
    const float* b1      = (const float*)d_in[11];
    const float* g1      = (const float*)d_in[12];
    const float* be1     = (const float*)d_in[13];
    const float* W2      = (const float*)d_in[14];
    const float* b2      = (const float*)d_in[15];
    const float* g2      = (const float*)d_in[16];
    const float* be2     = (const float*)d_in[17];
    const float* W3      = (const float*)d_in[18];
    const float* b3      = (const float*)d_in[19];
    const float* Wf      = (const float*)d_in[20];
    const float* bf      = (const float*)d_in[21];
    const float* gf      = (const float*)d_in[22];
    const float* bef     = (const float*)d_in[23];
    const float* Wl      = (const float*)d_in[24];
    const float* bl      = (const float*)d_in[25];
    float* out = (float*)d_out;

    size_t o = 0;
    auto alloc = [&](size_t nfloats) {
        float* p = (float*)((char*)d_ws + o);
        o += ((nfloats * sizeof(float) + 255) / 256) * 256;
        return p;
    };
    float* r1    = alloc(NN * 64);   // xl_bf during GAT; h1f/h2f/zb after
    float* r2    = alloc(NN * 64);   // CSR during GAT; bf16 arena after
    float* a_src = alloc(NN);
    float* a_dst = alloc(NN);
    float* gsum  = alloc(NG * 64);
    float* gcntf = alloc(NG);
    float* bnbuf = alloc(16384);     // psum[8][1024] | psq[8][1024]
    int* gcnt = (int*)gcntf;
    float* psum = bnbuf;
    float* psq  = bnbuf + 8192;

    // R1 aliases
    ushort_t* xl_bf = (ushort_t*)r1;   // [50000,64] bf16
    float* h1f = r1;                   // [1000,1024]
    float* h2f = r1 + 1048576;         // [1000,512]
    float* zb  = r1 + 1572864;         // [1000,512]

    // R2: CSR (dead after k_gather), bf16 arena after
    int2*  csr_sw  = (int2*)r2;                      // [800008] int2 (padded)
    int*   deg     = (int*)((char*)r2 + 6400128);    // [50000]
    int*   rowptr  = (int*)((char*)r2 + 6600128);    // [50000]
    int*   cursor  = (int*)((char*)r2 + 6800128);    // [50000]
    int*   blocksum= (int*)((char*)r2 + 7000128);    // [196]

    ushort_t* U = (ushort_t*)r2;
    ushort_t* cbuf_bf   = U + 0;        // [1000,512]
    ushort_t* pooled_bf = U + 524288;   // [1000,64]
    ushort_t* Wlg_bf    = U + 589824;   // [256,64]
    ushort_t* fpts_bf   = U + 655360;   // [1000,2048]
    ushort_t* W1_bf     = U + 2703360;  // [1024,2048]
    ushort_t* W2_bf     = U + 4800512;  // [512,1024]
    ushort_t* h1_bf     = U + 5324800;  // [1000,1024]
    ushort_t* h2_bf     = U + 655360;   // [1000,512] (reuses fpts region)
    ushort_t* W3_bf     = U + 1200128;  // [256,512]
    ushort_t* Wf_bf     = U + 1331200;  // [512,512]

    // ---- GAT: projection + CSR build + fused gather/pool ----
    k_xl<<<NN / 4, 256, 0, stream>>>(x, Wg, att_src, att_dst, xl_bf, a_src, a_dst, deg);
    k_deg<<<(NE + 255) / 256, 256, 0, stream>>>(ei, deg);
    k_scan1<<<NB, 256, 0, stream>>>(deg, blocksum, gsum, gcnt);
    k_scan2<<<NB, 256, 0, stream>>>(deg, blocksum, rowptr, cursor);
    k_scatter<<<(NE + 255) / 256, 256, 0, stream>>>(ei, a_src, a_dst, cursor, csr_sw);
    k_gather<<<NN / 4, 256, 0, stream>>>(csr_sw, rowptr, deg, xl_bf, a_src, a_dst,
                                         gat_b, batch, gsum, gcnt);

    // ---- conversions for gnn/gemm1/gemm2 + pooled finalize (one launch) ----
    {
        int ba = GOUTC * 64 / 2048;            // 8
        int bb = ba + NG * FPC / 2048;         // 1008
        int bc = bb + H1C * FPC / 2048;        // 2032
        int bd = bc + H2C * H1C / 2048;        // 2288
        k_f2b4<<<bd + 32, 256, 0, stream>>>(Wlg, Wlg_bf, ba, fpts, fpts_bf, bb,
                                            W1, W1_bf, bc, W2, W2_bf, bd,
                                            GOUTC * 64, NG * FPC, H1C * FPC, H2C * H1C,
                                            gsum, gcnt, pooled_bf);
    }

    // gnn_out -> cbuf[:, 0:256] (bf16)
    k_mgemm<false, true><<<dim3(GOUTC / 64, 16), 256, 0, stream>>>(
        pooled_bf, Wlg_bf, blg, cbuf_bf, NG, GOUTC, 64, 512);

    // ---- MLP layer 1 ----
    k_mgemm<false, false><<<dim3(H1C / 64, 16), 256, 0, stream>>>(
        fpts_bf, W1_bf, b1, h1f, NG, H1C, FPC, H1C);
    k_bnpart<<<dim3(H1C / 256, 8), 256, 0, stream>>>(h1f, psum, psq, H1C);
    k_bnrelu_bf<<<(NG * H1C / 4 + 255) / 256, 256, 0, stream>>>(
        h1f, psum, psq, g1, be1, h1_bf, H1C - 1, NG * H1C);

    // conversions for gemm3/gemmF
    {
        int ba = MOUTC * H2C / 2048;           // 64
        int bb = ba + D1C * 512 / 2048;        // 192
        k_f2b4<<<bb, 256, 0, stream>>>(W3, W3_bf, ba, Wf, Wf_bf, bb,
                                       (const float*)0, (ushort_t*)0, bb,
                                       (const float*)0, (ushort_t*)0, bb,
                                       MOUTC * H2C, D1C * 512, 0, 0,
                                       (const float*)0, (const int*)0, (ushort_t*)0);
    }

    // ---- MLP layer 2 ----
    k_mgemm<false, false><<<dim3(H2C / 64, 16), 256, 0, stream>>>(
        h1_bf, W2_bf, b2, h2f, NG, H2C, H1C, H2C);
    k_bnpart<<<dim3(H2C / 256, 8), 256, 0, stream>>>(h2f, psum, psq, H2C);
    k_bnrelu_bf<<<(NG * H2C / 4 + 255) / 256, 256, 0, stream>>>(
        h2f, psum, psq, g2, be2, h2_bf, H2C - 1, NG * H2C);

    // mlp_out -> cbuf[:, 256:512] (bf16)
    k_mgemm<false, true><<<dim3(MOUTC / 64, 16), 256, 0, stream>>>(
        h2_bf, W3_bf, b3, cbuf_bf + 256, NG, MOUTC, H2C, 512);

    // ---- fusion head ----
    k_mgemm<true, false><<<dim3(D1C / 64, 16), 256, 0, stream>>>(
        cbuf_bf, Wf_bf, bf, zb, NG, D1C, GOUTC + MOUTC, D1C);
    k_bnpart<<<dim3(D1C / 256, 8), 256, 0, stream>>>(zb, psum, psq, D1C);
    k_final<<<NG, 256, 0, stream>>>(zb, psum, psq, gf, bef, Wl, bl, out);
}